// Round 1
// baseline (954.812 us; speedup 1.0000x reference)
//
#include <hip/hip_runtime.h>
#include <hip/hip_bf16.h>

// Problem constants (fixed by the reference)
constexpr int N_NODES = 50000;
constexpr int N_EDGES = 800000;
constexpr int R_REL   = 8;
constexpr int D       = 256;           // DIN = DH = DOUT
constexpr int K_TOT   = R_REL * D + D; // 2304 = 8 relation blocks + root block

typedef __attribute__((ext_vector_type(8))) short bf16x8;
typedef __attribute__((ext_vector_type(4))) float f32x4;

__device__ inline float to_f32(float v) { return v; }
__device__ inline float to_f32(__hip_bfloat16 v) { return __bfloat162float(v); }
__device__ inline void store_out(float* p, float v) { *p = v; }
__device__ inline void store_out(__hip_bfloat16* p, float v) { *p = __float2bfloat16(v); }

// ---------------------------------------------------------------------------
// 1. Per-(dst, relation) edge counts
// ---------------------------------------------------------------------------
__global__ __launch_bounds__(256) void count_kernel(
    const int* __restrict__ ei, const int* __restrict__ et,
    int* __restrict__ cnt) {
  int e = blockIdx.x * 256 + threadIdx.x;
  if (e < N_EDGES) {
    int dst = ei[N_EDGES + e];
    int rt  = et[e];
    atomicAdd(&cnt[dst * R_REL + rt], 1);
  }
}

// ---------------------------------------------------------------------------
// 2. Exclusive scan of per-node degree (3-phase, multi-block)
// ---------------------------------------------------------------------------
__global__ __launch_bounds__(256) void scan_phaseA(
    const int* __restrict__ cnt, int* __restrict__ bsum) {
  __shared__ int sd[256];
  int tid = threadIdx.x;
  int n = blockIdx.x * 256 + tid;
  int d = 0;
  if (n < N_NODES) {
#pragma unroll
    for (int r = 0; r < R_REL; r++) d += cnt[n * R_REL + r];
  }
  sd[tid] = d;
  __syncthreads();
  for (int off = 128; off > 0; off >>= 1) {
    if (tid < off) sd[tid] += sd[tid + off];
    __syncthreads();
  }
  if (tid == 0) bsum[blockIdx.x] = sd[0];
}

__global__ __launch_bounds__(256) void scan_phaseB(
    const int* __restrict__ bsum, int* __restrict__ boff,
    int* __restrict__ estart, int NB) {
  __shared__ int sd[256];
  int tid = threadIdx.x;
  int v = (tid < NB) ? bsum[tid] : 0;
  sd[tid] = v;
  __syncthreads();
  for (int off = 1; off < 256; off <<= 1) {
    int t = (tid >= off) ? sd[tid - off] : 0;
    __syncthreads();
    sd[tid] += t;
    __syncthreads();
  }
  if (tid < NB) boff[tid] = sd[tid] - v;  // exclusive block offset
  if (tid == 0) estart[N_NODES] = N_EDGES;
}

__global__ __launch_bounds__(256) void scan_phaseC(
    const int* __restrict__ cnt, const int* __restrict__ boff,
    int* __restrict__ estart) {
  __shared__ int sd[256];
  int tid = threadIdx.x;
  int n = blockIdx.x * 256 + tid;
  int d = 0;
  if (n < N_NODES) {
#pragma unroll
    for (int r = 0; r < R_REL; r++) d += cnt[n * R_REL + r];
  }
  sd[tid] = d;
  __syncthreads();
  for (int off = 1; off < 256; off <<= 1) {
    int t = (tid >= off) ? sd[tid - off] : 0;
    __syncthreads();
    sd[tid] += t;
    __syncthreads();
  }
  if (n < N_NODES) estart[n] = boff[blockIdx.x] + sd[tid] - d;  // exclusive
}

// ---------------------------------------------------------------------------
// 3. Bucket edges by dst: packed = src | (rt << 20)
// ---------------------------------------------------------------------------
__global__ __launch_bounds__(256) void bucket_kernel(
    const int* __restrict__ ei, const int* __restrict__ et,
    const int* __restrict__ estart, int* __restrict__ cursor,
    int* __restrict__ packed) {
  int e = blockIdx.x * 256 + threadIdx.x;
  if (e < N_EDGES) {
    int src = ei[e];
    int dst = ei[N_EDGES + e];
    int rt  = et[e];
    int pos = estart[dst] + atomicAdd(&cursor[dst], 1);
    packed[pos] = src | (rt << 20);
  }
}

// ---------------------------------------------------------------------------
// 4. Build transposed, concatenated weight WT[o][k], k<2048: W_r = sum_b comp*basis,
//    k>=2048: root. Stored bf16, row-major [256][2304] (i.e. B^T for the GEMM).
// ---------------------------------------------------------------------------
__global__ __launch_bounds__(256) void make_w_kernel(
    const float* __restrict__ basis, const float* __restrict__ comp,
    const float* __restrict__ root, __hip_bfloat16* __restrict__ WT) {
  int o = blockIdx.x;  // 256 blocks, one output column each
  int tid = threadIdx.x;
  for (int chunk = 0; chunk < K_TOT / 256; chunk++) {
    int k = chunk * 256 + tid;
    float w;
    if (k < R_REL * D) {
      int r = k >> 8, i = k & 255;
      float s = 0.f;
#pragma unroll
      for (int b = 0; b < 4; b++)
        s += comp[r * 4 + b] * basis[(b * D + i) * D + o];
      w = s;
    } else {
      w = root[(k - R_REL * D) * D + o];
    }
    WT[(size_t)o * K_TOT + k] = __float2bfloat16(w);
  }
}

// ---------------------------------------------------------------------------
// 5. Aggregate: one block per dst node. Thread tid owns column tid across all
//    8 relation accumulators (LDS, bank-conflict-free). Writes A row
//    [agg_0 .. agg_7, x_self] in bf16.
// ---------------------------------------------------------------------------
template <typename Tin>
__global__ __launch_bounds__(256) void aggregate_kernel(
    const Tin* __restrict__ xin, const int* __restrict__ packed,
    const int* __restrict__ estart, const int* __restrict__ cnt,
    __hip_bfloat16* __restrict__ aggA) {
  int n = blockIdx.x;
  int tid = threadIdx.x;
  __shared__ float acc[R_REL][D];
#pragma unroll
  for (int r = 0; r < R_REL; r++) acc[r][tid] = 0.f;
  // no __syncthreads needed: thread tid exclusively owns acc[*][tid]

  int s = estart[n], e = estart[n + 1];
  for (int i = s; i < e; i++) {
    int p = packed[i];                 // wave-uniform
    int src = p & 0xFFFFF;
    int rt = p >> 20;                  // wave-uniform -> uniform branch
    float norm = 1.0f / (float)cnt[n * R_REL + rt];
    float v = to_f32(xin[(size_t)src * D + tid]);
    acc[rt][tid] += norm * v;
  }

  size_t base = (size_t)n * K_TOT;
#pragma unroll
  for (int r = 0; r < R_REL; r++)
    aggA[base + r * D + tid] = __float2bfloat16(acc[r][tid]);
  aggA[base + R_REL * D + tid] = __float2bfloat16(to_f32(xin[(size_t)n * D + tid]));
}

// ---------------------------------------------------------------------------
// 6. GEMM: C[M,256] = A[M,2304](bf16) @ WT^T + bias, optional ReLU.
//    128x128 tile, 4 waves, 16x16x32 bf16 MFMA, fp32 accum.
// ---------------------------------------------------------------------------
#define BM 128
#define BN 128
#define BK 32
#define LDK 40  // padded LDS k-stride (bf16 elems); 80 B keeps 16B alignment

template <bool RELU, typename OutT>
__global__ __launch_bounds__(256) void gemm_kernel(
    const __hip_bfloat16* __restrict__ A,   // [M, K_TOT]
    const __hip_bfloat16* __restrict__ Bt,  // [256, K_TOT] (transposed weights)
    const float* __restrict__ bias, OutT* __restrict__ C, int M) {
  __shared__ __align__(16) __hip_bfloat16 As[BM * LDK];
  __shared__ __align__(16) __hip_bfloat16 Bs[BN * LDK];
  int tid = threadIdx.x;
  int m0 = blockIdx.x * BM;
  int n0 = blockIdx.y * BN;
  int wave = tid >> 6;
  int lane = tid & 63;
  int wm = wave & 1, wn = wave >> 1;
  int l15 = lane & 15, quad = lane >> 4;

  f32x4 acc[4][4] = {};

  for (int k0 = 0; k0 < K_TOT; k0 += BK) {
    // stage A and B tiles: 128 rows x 32 cols each, int4 (16B) chunks
#pragma unroll
    for (int p = 0; p < 2; p++) {
      int c = tid + p * 256;
      int row = c >> 2;
      int col = (c & 3) * 8;
      int4 va = make_int4(0, 0, 0, 0);
      if (m0 + row < M)
        va = *(const int4*)(A + (size_t)(m0 + row) * K_TOT + k0 + col);
      *(int4*)(As + row * LDK + col) = va;
      int4 vb = *(const int4*)(Bt + (size_t)(n0 + row) * K_TOT + k0 + col);
      *(int4*)(Bs + row * LDK + col) = vb;
    }
    __syncthreads();

    bf16x8 af[4], bfr[4];
#pragma unroll
    for (int mt = 0; mt < 4; mt++)
      af[mt] = *(const bf16x8*)(As + (wm * 64 + mt * 16 + l15) * LDK + quad * 8);
#pragma unroll
    for (int nt = 0; nt < 4; nt++)
      bfr[nt] = *(const bf16x8*)(Bs + (wn * 64 + nt * 16 + l15) * LDK + quad * 8);
#pragma unroll
    for (int mt = 0; mt < 4; mt++)
#pragma unroll
      for (int nt = 0; nt < 4; nt++)
        acc[mt][nt] = __builtin_amdgcn_mfma_f32_16x16x32_bf16(
            af[mt], bfr[nt], acc[mt][nt], 0, 0, 0);
    __syncthreads();
  }

  // epilogue: C/D layout col = lane&15, row = quad*4 + reg
#pragma unroll
  for (int nt = 0; nt < 4; nt++) {
    int cg = n0 + wn * 64 + nt * 16 + l15;
    float bv = bias[cg];
#pragma unroll
    for (int mt = 0; mt < 4; mt++) {
#pragma unroll
      for (int r = 0; r < 4; r++) {
        int rg = m0 + wm * 64 + mt * 16 + quad * 4 + r;
        if (rg < M) {
          float v = acc[mt][nt][r] + bv;
          if (RELU) v = fmaxf(v, 0.f);
          store_out(C + (size_t)rg * D + cg, v);
        }
      }
    }
  }
}

// ---------------------------------------------------------------------------
// Launch
// ---------------------------------------------------------------------------
static inline char* carve(char*& p, size_t bytes) {
  char* r = p;
  p += (bytes + 255) & ~(size_t)255;
  return r;
}

extern "C" void kernel_launch(void* const* d_in, const int* in_sizes, int n_in,
                              void* d_out, int out_size, void* d_ws,
                              size_t ws_size, hipStream_t stream) {
  const float* x      = (const float*)d_in[0];
  const int*   ei     = (const int*)d_in[1];
  const int*   et     = (const int*)d_in[2];
  const float* basis1 = (const float*)d_in[3];
  const float* comp1  = (const float*)d_in[4];
  const float* root1  = (const float*)d_in[5];
  const float* bias1  = (const float*)d_in[6];
  const float* basis2 = (const float*)d_in[7];
  const float* comp2  = (const float*)d_in[8];
  const float* root2  = (const float*)d_in[9];
  const float* bias2  = (const float*)d_in[10];
  float* out = (float*)d_out;

  char* ws = (char*)d_ws;
  int* cnt    = (int*)carve(ws, (size_t)N_NODES * R_REL * 4);
  int* estart = (int*)carve(ws, (size_t)(N_NODES + 1) * 4);
  int* cursor = (int*)carve(ws, (size_t)N_NODES * 4);
  int* bsum   = (int*)carve(ws, 256 * 4);
  int* boff   = (int*)carve(ws, 256 * 4);
  int* packed = (int*)carve(ws, (size_t)N_EDGES * 4);
  __hip_bfloat16* WT1  = (__hip_bfloat16*)carve(ws, (size_t)D * K_TOT * 2);
  __hip_bfloat16* WT2  = (__hip_bfloat16*)carve(ws, (size_t)D * K_TOT * 2);
  __hip_bfloat16* h    = (__hip_bfloat16*)carve(ws, (size_t)N_NODES * D * 2);
  __hip_bfloat16* aggA = (__hip_bfloat16*)carve(ws, (size_t)N_NODES * K_TOT * 2);

  const int NB = (N_NODES + 255) / 256;  // 196
  const int EB = (N_EDGES + 255) / 256;  // 3125

  hipMemsetAsync(cnt, 0, (size_t)N_NODES * R_REL * 4, stream);
  hipMemsetAsync(cursor, 0, (size_t)N_NODES * 4, stream);

  count_kernel<<<EB, 256, 0, stream>>>(ei, et, cnt);
  scan_phaseA<<<NB, 256, 0, stream>>>(cnt, bsum);
  scan_phaseB<<<1, 256, 0, stream>>>(bsum, boff, estart, NB);
  scan_phaseC<<<NB, 256, 0, stream>>>(cnt, boff, estart);
  bucket_kernel<<<EB, 256, 0, stream>>>(ei, et, estart, cursor, packed);

  make_w_kernel<<<D, 256, 0, stream>>>(basis1, comp1, root1, WT1);
  make_w_kernel<<<D, 256, 0, stream>>>(basis2, comp2, root2, WT2);

  dim3 ggrid((N_NODES + BM - 1) / BM, D / BN);

  // Layer 1: aggregate from fp32 x, GEMM -> bf16 h with ReLU
  aggregate_kernel<float><<<N_NODES, 256, 0, stream>>>(x, packed, estart, cnt, aggA);
  gemm_kernel<true, __hip_bfloat16><<<ggrid, 256, 0, stream>>>(aggA, WT1, bias1, h, N_NODES);

  // Layer 2: aggregate from bf16 h, GEMM -> fp32 out
  aggregate_kernel<__hip_bfloat16><<<N_NODES, 256, 0, stream>>>(h, packed, estart, cnt, aggA);
  gemm_kernel<false, float><<<ggrid, 256, 0, stream>>>(aggA, WT2, bias2, out, N_NODES);
}

// Round 2
// 588.311 us; speedup vs baseline: 1.6230x; 1.6230x over previous
//
#include <hip/hip_runtime.h>
#include <hip/hip_bf16.h>

// Problem constants (fixed by the reference)
constexpr int N_NODES = 50000;
constexpr int N_EDGES = 800000;
constexpr int R_REL   = 8;
constexpr int BASES   = 4;
constexpr int D       = 256;                 // DIN = DH = DOUT
constexpr int KT      = BASES * D + D;       // 1280: 4 basis blocks + self block
// z layout: k < 1024 -> k = col*4 + b  (basis-space aggregate, interleaved)
//           k >= 1024 -> self feature col = k - 1024

typedef __attribute__((ext_vector_type(8))) short bf16x8;
typedef __attribute__((ext_vector_type(4))) float f32x4;

__device__ inline float bfu_lo(unsigned u) { return __uint_as_float(u << 16); }
__device__ inline float bfu_hi(unsigned u) { return __uint_as_float(u & 0xFFFF0000u); }
__device__ inline unsigned short f2bu(float f) {
  __hip_bfloat16 h = __float2bfloat16(f);
  return *reinterpret_cast<unsigned short*>(&h);
}
__device__ inline void store_out(float* p, float v) { *p = v; }
__device__ inline void store_out(__hip_bfloat16* p, float v) { *p = __float2bfloat16(v); }

// ---------------------------------------------------------------------------
// 1. Per-(dst, relation) edge counts
// ---------------------------------------------------------------------------
__global__ __launch_bounds__(256) void count_kernel(
    const int* __restrict__ ei, const int* __restrict__ et,
    int* __restrict__ cnt) {
  int e = blockIdx.x * 256 + threadIdx.x;
  if (e < N_EDGES) {
    int dst = ei[N_EDGES + e];
    int rt  = et[e];
    atomicAdd(&cnt[dst * R_REL + rt], 1);
  }
}

// ---------------------------------------------------------------------------
// 2. Exclusive scan of per-node degree (3-phase)
// ---------------------------------------------------------------------------
__global__ __launch_bounds__(256) void scan_phaseA(
    const int* __restrict__ cnt, int* __restrict__ bsum) {
  __shared__ int sd[256];
  int tid = threadIdx.x;
  int n = blockIdx.x * 256 + tid;
  int d = 0;
  if (n < N_NODES) {
#pragma unroll
    for (int r = 0; r < R_REL; r++) d += cnt[n * R_REL + r];
  }
  sd[tid] = d;
  __syncthreads();
  for (int off = 128; off > 0; off >>= 1) {
    if (tid < off) sd[tid] += sd[tid + off];
    __syncthreads();
  }
  if (tid == 0) bsum[blockIdx.x] = sd[0];
}

__global__ __launch_bounds__(256) void scan_phaseB(
    const int* __restrict__ bsum, int* __restrict__ boff,
    int* __restrict__ estart, int NB) {
  __shared__ int sd[256];
  int tid = threadIdx.x;
  int v = (tid < NB) ? bsum[tid] : 0;
  sd[tid] = v;
  __syncthreads();
  for (int off = 1; off < 256; off <<= 1) {
    int t = (tid >= off) ? sd[tid - off] : 0;
    __syncthreads();
    sd[tid] += t;
    __syncthreads();
  }
  if (tid < NB) boff[tid] = sd[tid] - v;
  if (tid == 0) estart[N_NODES] = N_EDGES;
}

__global__ __launch_bounds__(256) void scan_phaseC(
    const int* __restrict__ cnt, const int* __restrict__ boff,
    int* __restrict__ estart) {
  __shared__ int sd[256];
  int tid = threadIdx.x;
  int n = blockIdx.x * 256 + tid;
  int d = 0;
  if (n < N_NODES) {
#pragma unroll
    for (int r = 0; r < R_REL; r++) d += cnt[n * R_REL + r];
  }
  sd[tid] = d;
  __syncthreads();
  for (int off = 1; off < 256; off <<= 1) {
    int t = (tid >= off) ? sd[tid - off] : 0;
    __syncthreads();
    sd[tid] += t;
    __syncthreads();
  }
  if (n < N_NODES) estart[n] = boff[blockIdx.x] + sd[tid] - d;
}

// ---------------------------------------------------------------------------
// 3. Bucket edges by dst: packed = src | (rt << 20)
// ---------------------------------------------------------------------------
__global__ __launch_bounds__(256) void bucket_kernel(
    const int* __restrict__ ei, const int* __restrict__ et,
    const int* __restrict__ estart, int* __restrict__ cursor,
    int* __restrict__ packed) {
  int e = blockIdx.x * 256 + threadIdx.x;
  if (e < N_EDGES) {
    int src = ei[e];
    int dst = ei[N_EDGES + e];
    int rt  = et[e];
    int pos = estart[dst] + atomicAdd(&cursor[dst], 1);
    packed[pos] = src | (rt << 20);
  }
}

// ---------------------------------------------------------------------------
// 4. x (fp32) -> bf16, packed as uint pairs: x2[n*128 + c] holds cols 2c,2c+1
// ---------------------------------------------------------------------------
__global__ __launch_bounds__(256) void convert_kernel(
    const float* __restrict__ x, unsigned* __restrict__ x2) {
  int idx = blockIdx.x * 256 + threadIdx.x;  // over N*128
  if (idx < N_NODES * 128) {
    float2 v = *(const float2*)(x + (size_t)idx * 2);
    x2[idx] = (unsigned)f2bu(v.x) | ((unsigned)f2bu(v.y) << 16);
  }
}

// ---------------------------------------------------------------------------
// 5. Weight build: WT[o][k], bf16, k<1024: basis[b=k&3][i=k>>2][o];
//    k>=1024: root[k-1024][o].  (comp is folded into z during aggregation)
// ---------------------------------------------------------------------------
__global__ __launch_bounds__(256) void make_w_kernel(
    const float* __restrict__ basis, const float* __restrict__ root,
    __hip_bfloat16* __restrict__ WT) {
  int o = blockIdx.x;
  int tid = threadIdx.x;
#pragma unroll
  for (int chunk = 0; chunk < KT / 256; chunk++) {
    int k = chunk * 256 + tid;
    float w;
    if (k < BASES * D) {
      int b = k & 3, i = k >> 2;
      w = basis[((size_t)b * D + i) * D + o];
    } else {
      w = root[(size_t)(k - BASES * D) * D + o];
    }
    WT[(size_t)o * KT + k] = __float2bfloat16(w);
  }
}

// ---------------------------------------------------------------------------
// 6. Aggregate into basis space. One block per dst node, 4 waves each
//    striding the node's edge list. Lane owns cols {4*lane..4*lane+3} x 4
//    bases in registers; one LDS reduction at the end.
// ---------------------------------------------------------------------------
__global__ __launch_bounds__(256) void aggregate_kernel(
    const unsigned* __restrict__ x2,   // bf16 features as uint pairs [N][128]
    const int* __restrict__ packed,
    const int* __restrict__ estart,
    const int* __restrict__ cnt,
    const float* __restrict__ comp,    // [R][B]
    __hip_bfloat16* __restrict__ zA)   // [N][KT]
{
  int n = blockIdx.x;
  int tid = threadIdx.x;
  int wave = tid >> 6, lane = tid & 63;
  __shared__ float winv[R_REL][BASES];
  __shared__ float red[4][BASES][256];  // [wave][b][col] = 16 KB

  if (tid < R_REL * BASES) {
    int r = tid >> 2, b = tid & 3;
    int c = cnt[n * R_REL + r];
    winv[r][b] = comp[r * BASES + b] / (float)(c > 0 ? c : 1);
  }
  __syncthreads();

  float acc[BASES][4] = {};  // [b][j], col = lane*4 + j
  int s = estart[n], e = estart[n + 1];
  for (int i = s + wave; i < e; i += 4) {
    int p = packed[i];                 // wave-uniform
    int src = p & 0xFFFFF;
    int rt = p >> 20;                  // wave-uniform
    uint2 v = *(const uint2*)(x2 + (size_t)src * 128 + lane * 2);
    float xv0 = bfu_lo(v.x), xv1 = bfu_hi(v.x);
    float xv2 = bfu_lo(v.y), xv3 = bfu_hi(v.y);
#pragma unroll
    for (int b = 0; b < BASES; b++) {
      float w = winv[rt][b];           // LDS broadcast
      acc[b][0] += w * xv0;
      acc[b][1] += w * xv1;
      acc[b][2] += w * xv2;
      acc[b][3] += w * xv3;
    }
  }

#pragma unroll
  for (int b = 0; b < BASES; b++)
    *(float4*)&red[wave][b][lane * 4] = *(float4*)acc[b];
  __syncthreads();

  // thread t handles col t: sum 4 waves for each b, pack 4 bf16 -> 8B store
  float sv0 = red[0][0][tid] + red[1][0][tid] + red[2][0][tid] + red[3][0][tid];
  float sv1 = red[0][1][tid] + red[1][1][tid] + red[2][1][tid] + red[3][1][tid];
  float sv2 = red[0][2][tid] + red[1][2][tid] + red[2][2][tid] + red[3][2][tid];
  float sv3 = red[0][3][tid] + red[1][3][tid] + red[2][3][tid] + red[3][3][tid];
  ushort4 ov;
  ov.x = f2bu(sv0); ov.y = f2bu(sv1); ov.z = f2bu(sv2); ov.w = f2bu(sv3);
  *(ushort4*)(zA + (size_t)n * KT + tid * 4) = ov;

  // self block: straight bf16 copy of x2[n]
  if (tid < 64) {
    uint2 v = *(const uint2*)(x2 + (size_t)n * 128 + tid * 2);
    *(uint2*)((unsigned*)(zA + (size_t)n * KT + BASES * D) + tid * 2) = v;
  }
}

// ---------------------------------------------------------------------------
// 7. GEMM: C[M,256] = A[M,1280](bf16) @ WT^T + bias, optional ReLU.
//    128x256 tile, 8 waves (512 thr), 16x16x32 bf16 MFMA, fp32 accum.
// ---------------------------------------------------------------------------
#define BM 128
#define BN 256
#define BK 32
#define LDK 40  // padded LDS k-stride (bf16); 80 B rows keep 16B alignment

template <bool RELU, typename OutT>
__global__ __launch_bounds__(512) void gemm_kernel(
    const __hip_bfloat16* __restrict__ A,   // [M, KT]
    const __hip_bfloat16* __restrict__ Bt,  // [256, KT] (transposed weights)
    const float* __restrict__ bias, OutT* __restrict__ C, int M) {
  __shared__ __align__(16) __hip_bfloat16 As[BM * LDK];
  __shared__ __align__(16) __hip_bfloat16 Bs[BN * LDK];
  int tid = threadIdx.x;
  int m0 = blockIdx.x * BM;
  int wave = tid >> 6, lane = tid & 63;
  int wm = wave & 1, wn = wave >> 1;     // 2 x 4 wave grid
  int l15 = lane & 15, quad = lane >> 4;

  f32x4 acc[4][4] = {};

  for (int k0 = 0; k0 < KT; k0 += BK) {
    // As: 512 int4 chunks (1/thread); Bs: 1024 int4 chunks (2/thread)
    {
      int row = tid >> 2, col = (tid & 3) * 8;
      int4 va = make_int4(0, 0, 0, 0);
      if (m0 + row < M)
        va = *(const int4*)(A + (size_t)(m0 + row) * KT + k0 + col);
      *(int4*)(As + row * LDK + col) = va;
#pragma unroll
      for (int p = 0; p < 2; p++) {
        int idx = tid + p * 512;
        int br = idx >> 2, bc = (idx & 3) * 8;
        *(int4*)(Bs + br * LDK + bc) =
            *(const int4*)(Bt + (size_t)br * KT + k0 + bc);
      }
    }
    __syncthreads();

    bf16x8 af[4], bfr[4];
#pragma unroll
    for (int mt = 0; mt < 4; mt++)
      af[mt] = *(const bf16x8*)(As + (wm * 64 + mt * 16 + l15) * LDK + quad * 8);
#pragma unroll
    for (int nt = 0; nt < 4; nt++)
      bfr[nt] = *(const bf16x8*)(Bs + (wn * 64 + nt * 16 + l15) * LDK + quad * 8);
#pragma unroll
    for (int mt = 0; mt < 4; mt++)
#pragma unroll
      for (int nt = 0; nt < 4; nt++)
        acc[mt][nt] = __builtin_amdgcn_mfma_f32_16x16x32_bf16(
            af[mt], bfr[nt], acc[mt][nt], 0, 0, 0);
    __syncthreads();
  }

  // epilogue: C/D layout col = lane&15, row = quad*4 + reg
#pragma unroll
  for (int nt = 0; nt < 4; nt++) {
    int cg = wn * 64 + nt * 16 + l15;
    float bv = bias[cg];
#pragma unroll
    for (int mt = 0; mt < 4; mt++) {
#pragma unroll
      for (int r = 0; r < 4; r++) {
        int rg = m0 + wm * 64 + mt * 16 + quad * 4 + r;
        if (rg < M) {
          float v = acc[mt][nt][r] + bv;
          if (RELU) v = fmaxf(v, 0.f);
          store_out(C + (size_t)rg * D + cg, v);
        }
      }
    }
  }
}

// ---------------------------------------------------------------------------
// Launch
// ---------------------------------------------------------------------------
static inline char* carve(char*& p, size_t bytes) {
  char* r = p;
  p += (bytes + 255) & ~(size_t)255;
  return r;
}

extern "C" void kernel_launch(void* const* d_in, const int* in_sizes, int n_in,
                              void* d_out, int out_size, void* d_ws,
                              size_t ws_size, hipStream_t stream) {
  const float* x      = (const float*)d_in[0];
  const int*   ei     = (const int*)d_in[1];
  const int*   et     = (const int*)d_in[2];
  const float* basis1 = (const float*)d_in[3];
  const float* comp1  = (const float*)d_in[4];
  const float* root1  = (const float*)d_in[5];
  const float* bias1  = (const float*)d_in[6];
  const float* basis2 = (const float*)d_in[7];
  const float* comp2  = (const float*)d_in[8];
  const float* root2  = (const float*)d_in[9];
  const float* bias2  = (const float*)d_in[10];
  float* out = (float*)d_out;

  char* ws = (char*)d_ws;
  int* cnt    = (int*)carve(ws, (size_t)N_NODES * R_REL * 4);
  int* estart = (int*)carve(ws, (size_t)(N_NODES + 1) * 4);
  int* cursor = (int*)carve(ws, (size_t)N_NODES * 4);
  int* bsum   = (int*)carve(ws, 256 * 4);
  int* boff   = (int*)carve(ws, 256 * 4);
  int* packed = (int*)carve(ws, (size_t)N_EDGES * 4);
  __hip_bfloat16* WT1 = (__hip_bfloat16*)carve(ws, (size_t)D * KT * 2);
  __hip_bfloat16* WT2 = (__hip_bfloat16*)carve(ws, (size_t)D * KT * 2);
  unsigned* xb = (unsigned*)carve(ws, (size_t)N_NODES * D * 2);   // bf16 x
  __hip_bfloat16* h = (__hip_bfloat16*)carve(ws, (size_t)N_NODES * D * 2);
  __hip_bfloat16* zA = (__hip_bfloat16*)carve(ws, (size_t)N_NODES * KT * 2);

  const int NB = (N_NODES + 255) / 256;   // 196
  const int EB = (N_EDGES + 255) / 256;   // 3125
  const int CB = (N_NODES * 128 + 255) / 256;

  hipMemsetAsync(cnt, 0, (size_t)N_NODES * R_REL * 4, stream);
  hipMemsetAsync(cursor, 0, (size_t)N_NODES * 4, stream);

  count_kernel<<<EB, 256, 0, stream>>>(ei, et, cnt);
  scan_phaseA<<<NB, 256, 0, stream>>>(cnt, bsum);
  scan_phaseB<<<1, 256, 0, stream>>>(bsum, boff, estart, NB);
  scan_phaseC<<<NB, 256, 0, stream>>>(cnt, boff, estart);
  bucket_kernel<<<EB, 256, 0, stream>>>(ei, et, estart, cursor, packed);

  convert_kernel<<<CB, 256, 0, stream>>>(x, xb);
  make_w_kernel<<<D, 256, 0, stream>>>(basis1, root1, WT1);
  make_w_kernel<<<D, 256, 0, stream>>>(basis2, root2, WT2);

  dim3 ggrid((N_NODES + BM - 1) / BM, 1);  // 391 blocks

  // Layer 1
  aggregate_kernel<<<N_NODES, 256, 0, stream>>>(xb, packed, estart, cnt, comp1, zA);
  gemm_kernel<true, __hip_bfloat16><<<ggrid, 512, 0, stream>>>(zA, WT1, bias1, h, N_NODES);

  // Layer 2 (h is bf16 [N][256] — same packed-uint view as xb)
  aggregate_kernel<<<N_NODES, 256, 0, stream>>>((const unsigned*)h, packed, estart, cnt, comp2, zA);
  gemm_kernel<false, float><<<ggrid, 512, 0, stream>>>(zA, WT2, bias2, out, N_NODES);
}

// Round 3
// 567.445 us; speedup vs baseline: 1.6827x; 1.0368x over previous
//
#include <hip/hip_runtime.h>
#include <hip/hip_bf16.h>

// Problem constants (fixed by the reference)
constexpr int N_NODES = 50000;
constexpr int N_EDGES = 800000;
constexpr int R_REL   = 8;
constexpr int BASES   = 4;
constexpr int D       = 256;                 // DIN = DH = DOUT
constexpr int KT      = BASES * D + D;       // 1280: 4 basis blocks + self block
// z layout: k < 1024 -> k = col*4 + b (basis-space aggregate, interleaved)
//           k >= 1024 -> self feature col = k - 1024

typedef __attribute__((ext_vector_type(8))) short bf16x8;
typedef __attribute__((ext_vector_type(4))) float f32x4;

__device__ inline float bfu_lo(unsigned u) { return __uint_as_float(u << 16); }
__device__ inline float bfu_hi(unsigned u) { return __uint_as_float(u & 0xFFFF0000u); }
__device__ inline unsigned short f2bu(float f) {
  __hip_bfloat16 h = __float2bfloat16(f);
  return *reinterpret_cast<unsigned short*>(&h);
}
__device__ inline void store_out(float* p, float v) { *p = v; }
__device__ inline void store_out(__hip_bfloat16* p, float v) { *p = __float2bfloat16(v); }

// async 16B global -> LDS (wave-uniform lds base + lane*16)
__device__ inline void gload_lds16(void* lds, const void* g) {
  __builtin_amdgcn_global_load_lds(
      (const __attribute__((address_space(1))) unsigned*)g,
      (__attribute__((address_space(3))) unsigned*)lds, 16, 0, 0);
}

// ---------------------------------------------------------------------------
// 1. Per-(dst, relation) edge counts
// ---------------------------------------------------------------------------
__global__ __launch_bounds__(256) void count_kernel(
    const int* __restrict__ ei, const int* __restrict__ et,
    int* __restrict__ cnt) {
  int e = blockIdx.x * 256 + threadIdx.x;
  if (e < N_EDGES) {
    int dst = ei[N_EDGES + e];
    int rt  = et[e];
    atomicAdd(&cnt[dst * R_REL + rt], 1);
  }
}

// ---------------------------------------------------------------------------
// 2. Exclusive scan of per-node degree (3-phase)
// ---------------------------------------------------------------------------
__global__ __launch_bounds__(256) void scan_phaseA(
    const int* __restrict__ cnt, int* __restrict__ bsum) {
  __shared__ int sd[256];
  int tid = threadIdx.x;
  int n = blockIdx.x * 256 + tid;
  int d = 0;
  if (n < N_NODES) {
#pragma unroll
    for (int r = 0; r < R_REL; r++) d += cnt[n * R_REL + r];
  }
  sd[tid] = d;
  __syncthreads();
  for (int off = 128; off > 0; off >>= 1) {
    if (tid < off) sd[tid] += sd[tid + off];
    __syncthreads();
  }
  if (tid == 0) bsum[blockIdx.x] = sd[0];
}

__global__ __launch_bounds__(256) void scan_phaseB(
    const int* __restrict__ bsum, int* __restrict__ boff,
    int* __restrict__ estart, int NB) {
  __shared__ int sd[256];
  int tid = threadIdx.x;
  int v = (tid < NB) ? bsum[tid] : 0;
  sd[tid] = v;
  __syncthreads();
  for (int off = 1; off < 256; off <<= 1) {
    int t = (tid >= off) ? sd[tid - off] : 0;
    __syncthreads();
    sd[tid] += t;
    __syncthreads();
  }
  if (tid < NB) boff[tid] = sd[tid] - v;
  if (tid == 0) estart[N_NODES] = N_EDGES;
}

__global__ __launch_bounds__(256) void scan_phaseC(
    const int* __restrict__ cnt, const int* __restrict__ boff,
    int* __restrict__ estart) {
  __shared__ int sd[256];
  int tid = threadIdx.x;
  int n = blockIdx.x * 256 + tid;
  int d = 0;
  if (n < N_NODES) {
#pragma unroll
    for (int r = 0; r < R_REL; r++) d += cnt[n * R_REL + r];
  }
  sd[tid] = d;
  __syncthreads();
  for (int off = 1; off < 256; off <<= 1) {
    int t = (tid >= off) ? sd[tid - off] : 0;
    __syncthreads();
    sd[tid] += t;
    __syncthreads();
  }
  if (n < N_NODES) estart[n] = boff[blockIdx.x] + sd[tid] - d;
}

// ---------------------------------------------------------------------------
// 3. Bucket edges by dst: packed = src | (rt << 20)
// ---------------------------------------------------------------------------
__global__ __launch_bounds__(256) void bucket_kernel(
    const int* __restrict__ ei, const int* __restrict__ et,
    const int* __restrict__ estart, int* __restrict__ cursor,
    int* __restrict__ packed) {
  int e = blockIdx.x * 256 + threadIdx.x;
  if (e < N_EDGES) {
    int src = ei[e];
    int dst = ei[N_EDGES + e];
    int rt  = et[e];
    int pos = estart[dst] + atomicAdd(&cursor[dst], 1);
    packed[pos] = src | (rt << 20);
  }
}

// ---------------------------------------------------------------------------
// 4. x (fp32) -> bf16, packed as uint pairs: x2[n*128 + c] holds cols 2c,2c+1
// ---------------------------------------------------------------------------
__global__ __launch_bounds__(256) void convert_kernel(
    const float* __restrict__ x, unsigned* __restrict__ x2) {
  int idx = blockIdx.x * 256 + threadIdx.x;  // over N*128
  if (idx < N_NODES * 128) {
    float2 v = *(const float2*)(x + (size_t)idx * 2);
    x2[idx] = (unsigned)f2bu(v.x) | ((unsigned)f2bu(v.y) << 16);
  }
}

// ---------------------------------------------------------------------------
// 5. Weight build: WT[o][k] bf16 (transposed). Coalesced reads, LDS transpose.
//    k<1024: basis[b=k&3][i=k>>2][o]; k>=1024: root[k-1024][o].
//    Grid: KT/64 = 20 blocks, 256 threads.
// ---------------------------------------------------------------------------
__global__ __launch_bounds__(256) void make_w_kernel(
    const float* __restrict__ basis, const float* __restrict__ root,
    __hip_bfloat16* __restrict__ WT) {
  __shared__ __hip_bfloat16 tile[64][256];
  int k0 = blockIdx.x * 64;
  int tid = threadIdx.x;
#pragma unroll 4
  for (int r = 0; r < 64; r++) {
    int k = k0 + r;
    const float* srow = (k < BASES * D)
        ? basis + ((size_t)(k & 3) * D + (k >> 2)) * D
        : root + (size_t)(k - BASES * D) * D;
    tile[r][tid] = __float2bfloat16(srow[tid]);
  }
  __syncthreads();
  __hip_bfloat16* dst = WT + (size_t)tid * KT + k0;
#pragma unroll
  for (int c = 0; c < 8; c++) {
    union { short s[8]; int4 v; } u;
#pragma unroll
    for (int r = 0; r < 8; r++)
      u.s[r] = *reinterpret_cast<short*>(&tile[c * 8 + r][tid]);
    *(int4*)(dst + c * 8) = u.v;
  }
}

// ---------------------------------------------------------------------------
// 6. Aggregate into basis space. One block per dst node, 4 waves. Wave takes
//    contiguous groups of 4 edges -> 4 gathers in flight (MLP=4). Lane owns
//    cols {4*lane..4*lane+3} x 4 bases in registers; LDS reduce at end.
// ---------------------------------------------------------------------------
__device__ inline void edge_fma(float acc[BASES][4], uint2 v, float4 w) {
  float a0 = bfu_lo(v.x), a1 = bfu_hi(v.x), a2 = bfu_lo(v.y), a3 = bfu_hi(v.y);
  acc[0][0] += w.x * a0; acc[0][1] += w.x * a1; acc[0][2] += w.x * a2; acc[0][3] += w.x * a3;
  acc[1][0] += w.y * a0; acc[1][1] += w.y * a1; acc[1][2] += w.y * a2; acc[1][3] += w.y * a3;
  acc[2][0] += w.z * a0; acc[2][1] += w.z * a1; acc[2][2] += w.z * a2; acc[2][3] += w.z * a3;
  acc[3][0] += w.w * a0; acc[3][1] += w.w * a1; acc[3][2] += w.w * a2; acc[3][3] += w.w * a3;
}

__global__ __launch_bounds__(256) void aggregate_kernel(
    const unsigned* __restrict__ x2,   // bf16 features as uint pairs [N][128]
    const int* __restrict__ packed,
    const int* __restrict__ estart,
    const int* __restrict__ cnt,
    const float* __restrict__ comp,    // [R][B]
    __hip_bfloat16* __restrict__ zA)   // [N][KT]
{
  int n = blockIdx.x;
  int tid = threadIdx.x;
  int wave = tid >> 6, lane = tid & 63;
  __shared__ __align__(16) float winv[R_REL][BASES];
  __shared__ __align__(16) float red[4][BASES][256];  // 16 KB

  if (tid < R_REL * BASES) {
    int r = tid >> 2, b = tid & 3;
    int c = cnt[n * R_REL + r];
    winv[r][b] = comp[r * BASES + b] / (float)(c > 0 ? c : 1);
  }
  __syncthreads();

  float acc[BASES][4] = {};
  int s = estart[n], e = estart[n + 1];
  const float4 wzero = make_float4(0.f, 0.f, 0.f, 0.f);
  for (int base = s + wave * 4; base < e; base += 16) {
    int rem = e - base;  // >= 1, wave-uniform
    int p0 = packed[base];
    int p1 = (rem > 1) ? packed[base + 1] : 0;
    int p2 = (rem > 2) ? packed[base + 2] : 0;
    int p3 = (rem > 3) ? packed[base + 3] : 0;
    // 4 independent gathers in flight
    uint2 v0 = *(const uint2*)(x2 + (size_t)(p0 & 0xFFFFF) * 128 + lane * 2);
    uint2 v1 = *(const uint2*)(x2 + (size_t)(p1 & 0xFFFFF) * 128 + lane * 2);
    uint2 v2 = *(const uint2*)(x2 + (size_t)(p2 & 0xFFFFF) * 128 + lane * 2);
    uint2 v3 = *(const uint2*)(x2 + (size_t)(p3 & 0xFFFFF) * 128 + lane * 2);
    float4 w0 = *(const float4*)winv[p0 >> 20];
    float4 w1 = (rem > 1) ? *(const float4*)winv[p1 >> 20] : wzero;
    float4 w2 = (rem > 2) ? *(const float4*)winv[p2 >> 20] : wzero;
    float4 w3 = (rem > 3) ? *(const float4*)winv[p3 >> 20] : wzero;
    edge_fma(acc, v0, w0);
    edge_fma(acc, v1, w1);
    edge_fma(acc, v2, w2);
    edge_fma(acc, v3, w3);
  }

#pragma unroll
  for (int b = 0; b < BASES; b++)
    *(float4*)&red[wave][b][lane * 4] = *(float4*)acc[b];
  __syncthreads();

  // thread t handles col t: sum 4 waves per basis, pack 4 bf16 -> 8B store
  float sv0 = red[0][0][tid] + red[1][0][tid] + red[2][0][tid] + red[3][0][tid];
  float sv1 = red[0][1][tid] + red[1][1][tid] + red[2][1][tid] + red[3][1][tid];
  float sv2 = red[0][2][tid] + red[1][2][tid] + red[2][2][tid] + red[3][2][tid];
  float sv3 = red[0][3][tid] + red[1][3][tid] + red[2][3][tid] + red[3][3][tid];
  ushort4 ov;
  ov.x = f2bu(sv0); ov.y = f2bu(sv1); ov.z = f2bu(sv2); ov.w = f2bu(sv3);
  *(ushort4*)(zA + (size_t)n * KT + tid * 4) = ov;

  // self block: straight bf16 copy of x2[n]
  if (tid < 64) {
    uint2 v = *(const uint2*)(x2 + (size_t)n * 128 + tid * 2);
    *(uint2*)((unsigned*)(zA + (size_t)n * KT + BASES * D) + tid * 2) = v;
  }
}

// ---------------------------------------------------------------------------
// 7. GEMM (m97 structure): C[M,256] = A[M,1280](bf16) @ WT^T + bias.
//    128x128 tile, 4 waves, BK=32, unpadded LDS + global_load_lds width 16.
// ---------------------------------------------------------------------------
#define BM 128
#define BN 128
#define BK 32

template <bool RELU, typename OutT>
__global__ __launch_bounds__(256) void gemm_kernel(
    const __hip_bfloat16* __restrict__ A,   // [M, KT]
    const __hip_bfloat16* __restrict__ Bt,  // [256, KT] (transposed weights)
    const float* __restrict__ bias, OutT* __restrict__ C, int M) {
  __shared__ __align__(16) __hip_bfloat16 As[BM * BK];  // 8 KB
  __shared__ __align__(16) __hip_bfloat16 Bs[BN * BK];  // 8 KB
  int tid = threadIdx.x;
  int m0 = blockIdx.x * BM;
  int n0 = blockIdx.y * BN;
  int wave = tid >> 6, lane = tid & 63;
  int wm = wave & 1, wn = wave >> 1;
  int l15 = lane & 15, quad = lane >> 4;

  // staging geometry: issue q = wave*2+p covers rows q*16..q*16+15, lane l
  // -> row q*16 + l/4, col (l&3)*8 ; LDS dest = base + q*512 elems + l*16 B
  int colS  = (lane & 3) * 8;
  int rowS0 = wave * 32 + (lane >> 2);
  int rowS1 = rowS0 + 16;
  int grA0 = min(m0 + rowS0, M - 1);   // clamp: tail rows load dup data,
  int grA1 = min(m0 + rowS1, M - 1);   // discarded in epilogue
  const __hip_bfloat16* gA0 = A + (size_t)grA0 * KT + colS;
  const __hip_bfloat16* gA1 = A + (size_t)grA1 * KT + colS;
  const __hip_bfloat16* gB0 = Bt + (size_t)(n0 + rowS0) * KT + colS;
  const __hip_bfloat16* gB1 = Bt + (size_t)(n0 + rowS1) * KT + colS;
  __hip_bfloat16* lA0 = As + wave * 1024;
  __hip_bfloat16* lA1 = As + wave * 1024 + 512;
  __hip_bfloat16* lB0 = Bs + wave * 1024;
  __hip_bfloat16* lB1 = Bs + wave * 1024 + 512;

  f32x4 acc[4][4] = {};

  for (int k0 = 0; k0 < KT; k0 += BK) {
    gload_lds16(lA0, gA0 + k0);
    gload_lds16(lA1, gA1 + k0);
    gload_lds16(lB0, gB0 + k0);
    gload_lds16(lB1, gB1 + k0);
    __syncthreads();  // compiler drains vmcnt before barrier

    bf16x8 af[4], bfr[4];
#pragma unroll
    for (int mt = 0; mt < 4; mt++)
      af[mt] = *(const bf16x8*)(As + (wm * 64 + mt * 16 + l15) * BK + quad * 8);
#pragma unroll
    for (int nt = 0; nt < 4; nt++)
      bfr[nt] = *(const bf16x8*)(Bs + (wn * 64 + nt * 16 + l15) * BK + quad * 8);
#pragma unroll
    for (int mt = 0; mt < 4; mt++)
#pragma unroll
      for (int nt = 0; nt < 4; nt++)
        acc[mt][nt] = __builtin_amdgcn_mfma_f32_16x16x32_bf16(
            af[mt], bfr[nt], acc[mt][nt], 0, 0, 0);
    __syncthreads();
  }

  // epilogue: C/D layout col = lane&15, row = quad*4 + reg
#pragma unroll
  for (int nt = 0; nt < 4; nt++) {
    int cg = n0 + wn * 64 + nt * 16 + l15;
    float bv = bias[cg];
#pragma unroll
    for (int mt = 0; mt < 4; mt++) {
#pragma unroll
      for (int r = 0; r < 4; r++) {
        int rg = m0 + wm * 64 + mt * 16 + quad * 4 + r;
        if (rg < M) {
          float v = acc[mt][nt][r] + bv;
          if (RELU) v = fmaxf(v, 0.f);
          store_out(C + (size_t)rg * D + cg, v);
        }
      }
    }
  }
}

// ---------------------------------------------------------------------------
// Launch
// ---------------------------------------------------------------------------
static inline char* carve(char*& p, size_t bytes) {
  char* r = p;
  p += (bytes + 255) & ~(size_t)255;
  return r;
}

extern "C" void kernel_launch(void* const* d_in, const int* in_sizes, int n_in,
                              void* d_out, int out_size, void* d_ws,
                              size_t ws_size, hipStream_t stream) {
  const float* x      = (const float*)d_in[0];
  const int*   ei     = (const int*)d_in[1];
  const int*   et     = (const int*)d_in[2];
  const float* basis1 = (const float*)d_in[3];
  const float* comp1  = (const float*)d_in[4];
  const float* root1  = (const float*)d_in[5];
  const float* bias1  = (const float*)d_in[6];
  const float* basis2 = (const float*)d_in[7];
  const float* comp2  = (const float*)d_in[8];
  const float* root2  = (const float*)d_in[9];
  const float* bias2  = (const float*)d_in[10];
  float* out = (float*)d_out;

  char* ws = (char*)d_ws;
  int* cnt    = (int*)carve(ws, (size_t)N_NODES * R_REL * 4);
  int* estart = (int*)carve(ws, (size_t)(N_NODES + 1) * 4);
  int* cursor = (int*)carve(ws, (size_t)N_NODES * 4);
  int* bsum   = (int*)carve(ws, 256 * 4);
  int* boff   = (int*)carve(ws, 256 * 4);
  int* packed = (int*)carve(ws, (size_t)N_EDGES * 4);
  __hip_bfloat16* WT1 = (__hip_bfloat16*)carve(ws, (size_t)D * KT * 2);
  __hip_bfloat16* WT2 = (__hip_bfloat16*)carve(ws, (size_t)D * KT * 2);
  unsigned* xb = (unsigned*)carve(ws, (size_t)N_NODES * D * 2);   // bf16 x
  __hip_bfloat16* h = (__hip_bfloat16*)carve(ws, (size_t)N_NODES * D * 2);
  __hip_bfloat16* zA = (__hip_bfloat16*)carve(ws, (size_t)N_NODES * KT * 2);

  const int NB = (N_NODES + 255) / 256;   // 196
  const int EB = (N_EDGES + 255) / 256;   // 3125
  const int CB = (N_NODES * 128 + 255) / 256;

  hipMemsetAsync(cnt, 0, (size_t)N_NODES * R_REL * 4, stream);
  hipMemsetAsync(cursor, 0, (size_t)N_NODES * 4, stream);

  count_kernel<<<EB, 256, 0, stream>>>(ei, et, cnt);
  scan_phaseA<<<NB, 256, 0, stream>>>(cnt, bsum);
  scan_phaseB<<<1, 256, 0, stream>>>(bsum, boff, estart, NB);
  scan_phaseC<<<NB, 256, 0, stream>>>(cnt, boff, estart);
  bucket_kernel<<<EB, 256, 0, stream>>>(ei, et, estart, cursor, packed);

  convert_kernel<<<CB, 256, 0, stream>>>(x, xb);
  make_w_kernel<<<KT / 64, 256, 0, stream>>>(basis1, root1, WT1);
  make_w_kernel<<<KT / 64, 256, 0, stream>>>(basis2, root2, WT2);

  dim3 ggrid((N_NODES + BM - 1) / BM, D / BN);  // 391 x 2

  // Layer 1
  aggregate_kernel<<<N_NODES, 256, 0, stream>>>(xb, packed, estart, cnt, comp1, zA);
  gemm_kernel<true, __hip_bfloat16><<<ggrid, 256, 0, stream>>>(zA, WT1, bias1, h, N_NODES);

  // Layer 2 (h is bf16 [N][256] — same packed-uint view as xb)
  aggregate_kernel<<<N_NODES, 256, 0, stream>>>((const unsigned*)h, packed, estart, cnt, comp2, zA);
  gemm_kernel<false, float><<<ggrid, 256, 0, stream>>>(zA, WT2, bias2, out, N_NODES);
}

// Round 4
// 499.188 us; speedup vs baseline: 1.9127x; 1.1367x over previous
//
#include <hip/hip_runtime.h>
#include <hip/hip_bf16.h>

// Problem constants (fixed by the reference)
constexpr int N_NODES = 50000;
constexpr int N_EDGES = 800000;
constexpr int R_REL   = 8;
constexpr int BASES   = 4;
constexpr int D       = 256;                 // DIN = DH = DOUT
constexpr int KT      = BASES * D + D;       // 1280: 4 basis blocks + self block
// z layout: k < 1024 -> k = col*4 + b (basis-space aggregate, interleaved)
//           k >= 1024 -> self feature col = k - 1024

typedef __attribute__((ext_vector_type(8))) short bf16x8;
typedef __attribute__((ext_vector_type(4))) float f32x4;

__device__ inline float bfu_lo(unsigned u) { return __uint_as_float(u << 16); }
__device__ inline float bfu_hi(unsigned u) { return __uint_as_float(u & 0xFFFF0000u); }
__device__ inline unsigned short f2bu(float f) {
  __hip_bfloat16 h = __float2bfloat16(f);
  return *reinterpret_cast<unsigned short*>(&h);
}
__device__ inline void store_out(float* p, float v) { *p = v; }
__device__ inline void store_out(__hip_bfloat16* p, float v) { *p = __float2bfloat16(v); }

// async 16B global -> LDS (wave-uniform lds base + lane*16)
__device__ inline void gload_lds16(void* lds, const void* g) {
  __builtin_amdgcn_global_load_lds(
      (const __attribute__((address_space(1))) unsigned*)g,
      (__attribute__((address_space(3))) unsigned*)lds, 16, 0, 0);
}

// ---------------------------------------------------------------------------
// 1. Per-(dst, relation) edge counts
// ---------------------------------------------------------------------------
__global__ __launch_bounds__(256) void count_kernel(
    const int* __restrict__ ei, const int* __restrict__ et,
    int* __restrict__ cnt) {
  int e = blockIdx.x * 256 + threadIdx.x;
  if (e < N_EDGES) {
    int dst = ei[N_EDGES + e];
    int rt  = et[e];
    atomicAdd(&cnt[dst * R_REL + rt], 1);
  }
}

// ---------------------------------------------------------------------------
// 2. Exclusive scan of per-node degree (3-phase)
// ---------------------------------------------------------------------------
__global__ __launch_bounds__(256) void scan_phaseA(
    const int* __restrict__ cnt, int* __restrict__ bsum) {
  __shared__ int sd[256];
  int tid = threadIdx.x;
  int n = blockIdx.x * 256 + tid;
  int d = 0;
  if (n < N_NODES) {
#pragma unroll
    for (int r = 0; r < R_REL; r++) d += cnt[n * R_REL + r];
  }
  sd[tid] = d;
  __syncthreads();
  for (int off = 128; off > 0; off >>= 1) {
    if (tid < off) sd[tid] += sd[tid + off];
    __syncthreads();
  }
  if (tid == 0) bsum[blockIdx.x] = sd[0];
}

__global__ __launch_bounds__(256) void scan_phaseB(
    const int* __restrict__ bsum, int* __restrict__ boff,
    int* __restrict__ estart, int NB) {
  __shared__ int sd[256];
  int tid = threadIdx.x;
  int v = (tid < NB) ? bsum[tid] : 0;
  sd[tid] = v;
  __syncthreads();
  for (int off = 1; off < 256; off <<= 1) {
    int t = (tid >= off) ? sd[tid - off] : 0;
    __syncthreads();
    sd[tid] += t;
    __syncthreads();
  }
  if (tid < NB) boff[tid] = sd[tid] - v;
  if (tid == 0) estart[N_NODES] = N_EDGES;
}

__global__ __launch_bounds__(256) void scan_phaseC(
    const int* __restrict__ cnt, const int* __restrict__ boff,
    int* __restrict__ estart) {
  __shared__ int sd[256];
  int tid = threadIdx.x;
  int n = blockIdx.x * 256 + tid;
  int d = 0;
  if (n < N_NODES) {
#pragma unroll
    for (int r = 0; r < R_REL; r++) d += cnt[n * R_REL + r];
  }
  sd[tid] = d;
  __syncthreads();
  for (int off = 1; off < 256; off <<= 1) {
    int t = (tid >= off) ? sd[tid - off] : 0;
    __syncthreads();
    sd[tid] += t;
    __syncthreads();
  }
  if (n < N_NODES) estart[n] = boff[blockIdx.x] + sd[tid] - d;
}

// ---------------------------------------------------------------------------
// 3. Bucket edges by dst: packed = src | (rt << 20)
// ---------------------------------------------------------------------------
__global__ __launch_bounds__(256) void bucket_kernel(
    const int* __restrict__ ei, const int* __restrict__ et,
    const int* __restrict__ estart, int* __restrict__ cursor,
    int* __restrict__ packed) {
  int e = blockIdx.x * 256 + threadIdx.x;
  if (e < N_EDGES) {
    int src = ei[e];
    int dst = ei[N_EDGES + e];
    int rt  = et[e];
    int pos = estart[dst] + atomicAdd(&cursor[dst], 1);
    packed[pos] = src | (rt << 20);
  }
}

// ---------------------------------------------------------------------------
// 4. x (fp32) -> bf16, packed as uint pairs: x2[n*128 + c] holds cols 2c,2c+1
// ---------------------------------------------------------------------------
__global__ __launch_bounds__(256) void convert_kernel(
    const float* __restrict__ x, unsigned* __restrict__ x2) {
  int idx = blockIdx.x * 256 + threadIdx.x;  // over N*128
  if (idx < N_NODES * 128) {
    float2 v = *(const float2*)(x + (size_t)idx * 2);
    x2[idx] = (unsigned)f2bu(v.x) | ((unsigned)f2bu(v.y) << 16);
  }
}

// ---------------------------------------------------------------------------
// 4b. Precompute per-(node,relation) basis weights: wtab[n*8+r] = comp[r][:]/cnt
// ---------------------------------------------------------------------------
__global__ __launch_bounds__(256) void winv_kernel(
    const int* __restrict__ cnt, const float* __restrict__ comp,
    float4* __restrict__ wtab) {
  int idx = blockIdx.x * 256 + threadIdx.x;  // n*8 + r
  if (idx < N_NODES * R_REL) {
    int r = idx & 7;
    int c = cnt[idx];
    float inv = 1.0f / (float)(c > 0 ? c : 1);
    float4 w;
    w.x = comp[r * BASES + 0] * inv;
    w.y = comp[r * BASES + 1] * inv;
    w.z = comp[r * BASES + 2] * inv;
    w.w = comp[r * BASES + 3] * inv;
    wtab[idx] = w;
  }
}

// ---------------------------------------------------------------------------
// 5. Weight build: WT[o][k] bf16 (transposed). Coalesced reads, LDS transpose.
// ---------------------------------------------------------------------------
__global__ __launch_bounds__(256) void make_w_kernel(
    const float* __restrict__ basis, const float* __restrict__ root,
    __hip_bfloat16* __restrict__ WT) {
  __shared__ __hip_bfloat16 tile[64][256];
  int k0 = blockIdx.x * 64;
  int tid = threadIdx.x;
#pragma unroll 4
  for (int r = 0; r < 64; r++) {
    int k = k0 + r;
    const float* srow = (k < BASES * D)
        ? basis + ((size_t)(k & 3) * D + (k >> 2)) * D
        : root + (size_t)(k - BASES * D) * D;
    tile[r][tid] = __float2bfloat16(srow[tid]);
  }
  __syncthreads();
  __hip_bfloat16* dst = WT + (size_t)tid * KT + k0;
#pragma unroll
  for (int c = 0; c < 8; c++) {
    union { short s[8]; int4 v; } u;
#pragma unroll
    for (int r = 0; r < 8; r++)
      u.s[r] = *reinterpret_cast<short*>(&tile[c * 8 + r][tid]);
    *(int4*)(dst + c * 8) = u.v;
  }
}

// ---------------------------------------------------------------------------
// 6. Aggregate into basis space. WAVE per node (4 nodes/block), no LDS, no
//    barriers. Lane owns cols {4*lane..4*lane+3} x 4 bases in 16 VGPRs.
//    Edge loop unrolled x4 -> 4 gathers + 4 weight loads in flight.
// ---------------------------------------------------------------------------
__device__ inline void edge_fma(float acc[BASES][4], uint2 v, float4 w) {
  float a0 = bfu_lo(v.x), a1 = bfu_hi(v.x), a2 = bfu_lo(v.y), a3 = bfu_hi(v.y);
  acc[0][0] += w.x * a0; acc[0][1] += w.x * a1; acc[0][2] += w.x * a2; acc[0][3] += w.x * a3;
  acc[1][0] += w.y * a0; acc[1][1] += w.y * a1; acc[1][2] += w.y * a2; acc[1][3] += w.y * a3;
  acc[2][0] += w.z * a0; acc[2][1] += w.z * a1; acc[2][2] += w.z * a2; acc[2][3] += w.z * a3;
  acc[3][0] += w.w * a0; acc[3][1] += w.w * a1; acc[3][2] += w.w * a2; acc[3][3] += w.w * a3;
}

__global__ __launch_bounds__(256) void aggregate_kernel(
    const unsigned* __restrict__ x2,   // bf16 features as uint pairs [N][128]
    const int* __restrict__ packed,
    const int* __restrict__ estart,
    const float4* __restrict__ wtab,   // [N*8] per-(node,rel) basis weights
    __hip_bfloat16* __restrict__ zA)   // [N][KT]
{
  int tid = threadIdx.x;
  int wave = tid >> 6, lane = tid & 63;
  int n = blockIdx.x * 4 + wave;       // wave-uniform node
  const float4 wzero = make_float4(0.f, 0.f, 0.f, 0.f);

  float acc[BASES][4] = {};
  int s = estart[n], e = estart[n + 1];
  const float4* wt = wtab + (size_t)n * R_REL;

  for (int base = s; base < e; base += 4) {
    int rem = e - base;  // >= 1, wave-uniform
    int i1 = base + (rem > 1 ? 1 : 0);
    int i2 = base + (rem > 2 ? 2 : 0);
    int i3 = base + (rem > 3 ? 3 : 0);
    int p0 = packed[base];
    int p1 = packed[i1];
    int p2 = packed[i2];
    int p3 = packed[i3];
    // 4 independent gathers in flight
    uint2 v0 = *(const uint2*)(x2 + (size_t)(p0 & 0xFFFFF) * 128 + lane * 2);
    uint2 v1 = *(const uint2*)(x2 + (size_t)(p1 & 0xFFFFF) * 128 + lane * 2);
    uint2 v2 = *(const uint2*)(x2 + (size_t)(p2 & 0xFFFFF) * 128 + lane * 2);
    uint2 v3 = *(const uint2*)(x2 + (size_t)(p3 & 0xFFFFF) * 128 + lane * 2);
    float4 w0 = wt[p0 >> 20];
    float4 w1 = (rem > 1) ? wt[p1 >> 20] : wzero;
    float4 w2 = (rem > 2) ? wt[p2 >> 20] : wzero;
    float4 w3 = (rem > 3) ? wt[p3 >> 20] : wzero;
    edge_fma(acc, v0, w0);
    edge_fma(acc, v1, w1);
    edge_fma(acc, v2, w2);
    edge_fma(acc, v3, w3);
  }

  // store: k = (4*lane+j)*4 + b = 16*lane + 4*j + b -> 32 contiguous bytes
  union { short s[8]; int4 v; } u0, u1;
#pragma unroll
  for (int j = 0; j < 2; j++)
#pragma unroll
    for (int b = 0; b < BASES; b++) {
      u0.s[4 * j + b] = (short)f2bu(acc[b][j]);
      u1.s[4 * j + b] = (short)f2bu(acc[b][j + 2]);
    }
  __hip_bfloat16* zrow = zA + (size_t)n * KT;
  *(int4*)(zrow + 16 * lane) = u0.v;
  *(int4*)(zrow + 16 * lane + 8) = u1.v;

  // self block: straight bf16 copy of x2[n]
  uint2 sv = *(const uint2*)(x2 + (size_t)n * 128 + lane * 2);
  *(uint2*)((unsigned*)(zrow + BASES * D) + lane * 2) = sv;
}

// ---------------------------------------------------------------------------
// 7. GEMM: C[M,256] = A[M,1280](bf16) @ WT^T + bias. BM=128, BN=256 (full N,
//    A read once), 512 threads / 8 waves, BK=32, global_load_lds staging.
// ---------------------------------------------------------------------------
#define BM 128
#define BN 256
#define BK 32

template <bool RELU, typename OutT>
__global__ __launch_bounds__(512) void gemm_kernel(
    const __hip_bfloat16* __restrict__ A,   // [M, KT]
    const __hip_bfloat16* __restrict__ Bt,  // [256, KT] (transposed weights)
    const float* __restrict__ bias, OutT* __restrict__ C, int M) {
  __shared__ __align__(16) __hip_bfloat16 As[BM * BK];  // 8 KB
  __shared__ __align__(16) __hip_bfloat16 Bs[BN * BK];  // 16 KB
  int tid = threadIdx.x;
  int m0 = blockIdx.x * BM;
  int wave = tid >> 6, lane = tid & 63;
  int wm = wave & 1, wn = wave >> 1;   // 2 x 4 wave grid, 64x64 tiles
  int l15 = lane & 15, quad = lane >> 4;

  // staging geometry: lane covers row = base + lane/4, col (lane&3)*8;
  // LDS dest = wave-uniform base + lane*16 B
  int colS = (lane & 3) * 8;
  int rowA = wave * 16 + (lane >> 2);           // 0..127 across 8 waves
  int grA  = min(m0 + rowA, M - 1);             // clamp; epilogue masks tail
  const __hip_bfloat16* gA  = A + (size_t)grA * KT + colS;
  const __hip_bfloat16* gB0 = Bt + (size_t)(wave * 32 + (lane >> 2)) * KT + colS;
  const __hip_bfloat16* gB1 = gB0 + 16 * KT;
  __hip_bfloat16* lA  = As + wave * 512;
  __hip_bfloat16* lB0 = Bs + wave * 1024;
  __hip_bfloat16* lB1 = Bs + wave * 1024 + 512;

  f32x4 acc[4][4] = {};

  for (int k0 = 0; k0 < KT; k0 += BK) {
    gload_lds16(lA, gA + k0);
    gload_lds16(lB0, gB0 + k0);
    gload_lds16(lB1, gB1 + k0);
    __syncthreads();

    bf16x8 af[4], bfr[4];
#pragma unroll
    for (int mt = 0; mt < 4; mt++)
      af[mt] = *(const bf16x8*)(As + (wm * 64 + mt * 16 + l15) * BK + quad * 8);
#pragma unroll
    for (int nt = 0; nt < 4; nt++)
      bfr[nt] = *(const bf16x8*)(Bs + (wn * 64 + nt * 16 + l15) * BK + quad * 8);
#pragma unroll
    for (int mt = 0; mt < 4; mt++)
#pragma unroll
      for (int nt = 0; nt < 4; nt++)
        acc[mt][nt] = __builtin_amdgcn_mfma_f32_16x16x32_bf16(
            af[mt], bfr[nt], acc[mt][nt], 0, 0, 0);
    __syncthreads();
  }

  // epilogue: C/D layout col = lane&15, row = quad*4 + reg
#pragma unroll
  for (int nt = 0; nt < 4; nt++) {
    int cg = wn * 64 + nt * 16 + l15;
    float bv = bias[cg];
#pragma unroll
    for (int mt = 0; mt < 4; mt++) {
#pragma unroll
      for (int r = 0; r < 4; r++) {
        int rg = m0 + wm * 64 + mt * 16 + quad * 4 + r;
        if (rg < M) {
          float v = acc[mt][nt][r] + bv;
          if (RELU) v = fmaxf(v, 0.f);
          store_out(C + (size_t)rg * D + cg, v);
        }
      }
    }
  }
}

// ---------------------------------------------------------------------------
// Launch
// ---------------------------------------------------------------------------
static inline char* carve(char*& p, size_t bytes) {
  char* r = p;
  p += (bytes + 255) & ~(size_t)255;
  return r;
}

extern "C" void kernel_launch(void* const* d_in, const int* in_sizes, int n_in,
                              void* d_out, int out_size, void* d_ws,
                              size_t ws_size, hipStream_t stream) {
  const float* x      = (const float*)d_in[0];
  const int*   ei     = (const int*)d_in[1];
  const int*   et     = (const int*)d_in[2];
  const float* basis1 = (const float*)d_in[3];
  const float* comp1  = (const float*)d_in[4];
  const float* root1  = (const float*)d_in[5];
  const float* bias1  = (const float*)d_in[6];
  const float* basis2 = (const float*)d_in[7];
  const float* comp2  = (const float*)d_in[8];
  const float* root2  = (const float*)d_in[9];
  const float* bias2  = (const float*)d_in[10];
  float* out = (float*)d_out;

  char* ws = (char*)d_ws;
  int* cnt    = (int*)carve(ws, (size_t)N_NODES * R_REL * 4);
  int* estart = (int*)carve(ws, (size_t)(N_NODES + 1) * 4);
  int* cursor = (int*)carve(ws, (size_t)N_NODES * 4);
  int* bsum   = (int*)carve(ws, 256 * 4);
  int* boff   = (int*)carve(ws, 256 * 4);
  int* packed = (int*)carve(ws, (size_t)N_EDGES * 4);
  float4* wtab1 = (float4*)carve(ws, (size_t)N_NODES * R_REL * 16);
  float4* wtab2 = (float4*)carve(ws, (size_t)N_NODES * R_REL * 16);
  __hip_bfloat16* WT1 = (__hip_bfloat16*)carve(ws, (size_t)D * KT * 2);
  __hip_bfloat16* WT2 = (__hip_bfloat16*)carve(ws, (size_t)D * KT * 2);
  unsigned* xb = (unsigned*)carve(ws, (size_t)N_NODES * D * 2);   // bf16 x
  __hip_bfloat16* h = (__hip_bfloat16*)carve(ws, (size_t)N_NODES * D * 2);
  __hip_bfloat16* zA = (__hip_bfloat16*)carve(ws, (size_t)N_NODES * KT * 2);

  const int NB = (N_NODES + 255) / 256;   // 196
  const int EB = (N_EDGES + 255) / 256;   // 3125
  const int CB = (N_NODES * 128 + 255) / 256;
  const int WB = (N_NODES * R_REL + 255) / 256;

  hipMemsetAsync(cnt, 0, (size_t)N_NODES * R_REL * 4, stream);
  hipMemsetAsync(cursor, 0, (size_t)N_NODES * 4, stream);

  count_kernel<<<EB, 256, 0, stream>>>(ei, et, cnt);
  scan_phaseA<<<NB, 256, 0, stream>>>(cnt, bsum);
  scan_phaseB<<<1, 256, 0, stream>>>(bsum, boff, estart, NB);
  scan_phaseC<<<NB, 256, 0, stream>>>(cnt, boff, estart);
  bucket_kernel<<<EB, 256, 0, stream>>>(ei, et, estart, cursor, packed);

  convert_kernel<<<CB, 256, 0, stream>>>(x, xb);
  winv_kernel<<<WB, 256, 0, stream>>>(cnt, comp1, wtab1);
  winv_kernel<<<WB, 256, 0, stream>>>(cnt, comp2, wtab2);
  make_w_kernel<<<KT / 64, 256, 0, stream>>>(basis1, root1, WT1);
  make_w_kernel<<<KT / 64, 256, 0, stream>>>(basis2, root2, WT2);

  dim3 ggrid((N_NODES + BM - 1) / BM, 1);  // 391 blocks, full N per block
  const int AB = (N_NODES + 3) / 4;        // 12500 blocks, wave per node

  // Layer 1
  aggregate_kernel<<<AB, 256, 0, stream>>>(xb, packed, estart, wtab1, zA);
  gemm_kernel<true, __hip_bfloat16><<<ggrid, 512, 0, stream>>>(zA, WT1, bias1, h, N_NODES);

  // Layer 2 (h is bf16 [N][256] — same packed-uint view as xb)
  aggregate_kernel<<<AB, 256, 0, stream>>>((const unsigned*)h, packed, estart, wtab2, zA);
  gemm_kernel<false, float><<<ggrid, 512, 0, stream>>>(zA, WT2, bias2, out, N_NODES);
}